// Round 12
// baseline (222.482 us; speedup 1.0000x reference)
//
#include <hip/hip_runtime.h>

#define DN  128
#define H1N 512
#define H2N 256
#define TILE_A 4096
#define BKT_CAP 6144   // fixed bucket capacity: mean 4096, +32 sigma

typedef __attribute__((ext_vector_type(8))) short short8_t;   // 8 bf16
typedef __attribute__((ext_vector_type(4))) float f32x4;      // MFMA acc

__device__ inline ushort f2bf(float f) {
  union { float f; unsigned u; } v; v.f = f;
  unsigned r = v.u + 0x7FFF + ((v.u >> 16) & 1);   // RNE
  return (ushort)(r >> 16);
}
__device__ inline float asf(unsigned u) {
  union { unsigned u; float f; } v; v.u = u;
  return v.f;
}

// -------- CSR build, pass A: tile-reorder bucketize into fixed-cap buckets ---

__global__ __launch_bounds__(256) void k_bucketA(const int* __restrict__ ei,
                                                 int* __restrict__ bcur,
                                                 uint* __restrict__ pairs,
                                                 int E, int NB) {
  __shared__ int hist[512];
  __shared__ int start[512];
  __shared__ int cur[512];
  __shared__ int gbase[512];
  __shared__ uint lp[TILE_A];      // 16 KB
  __shared__ ushort bid[TILE_A];   // 8 KB
  int t = threadIdx.x;
  int base = blockIdx.x * TILE_A;
  int cnt = E - base; if (cnt > TILE_A) cnt = TILE_A;

  for (int i = t; i < 512; i += 256) hist[i] = 0;
  __syncthreads();

  int sreg[16], dreg[16];
#pragma unroll
  for (int k = 0; k < 16; ++k) {
    int idx = t + 256 * k;
    bool v = idx < cnt;
    sreg[k] = v ? ei[base + idx] : 0;
    dreg[k] = v ? ei[E + base + idx] : -1;
    if (v) atomicAdd(&hist[dreg[k] >> 8], 1);
  }
  __syncthreads();

  for (int i = t; i < 512; i += 256) start[i] = hist[i];
  __syncthreads();
  for (int o = 1; o < 512; o <<= 1) {
    int i0 = t, i1 = t + 256;
    int v0 = (i0 >= o) ? start[i0 - o] : 0;
    int v1 = (i1 >= o) ? start[i1 - o] : 0;
    __syncthreads();
    start[i0] += v0;
    start[i1] += v1;
    __syncthreads();
  }
  for (int i = t; i < 512; i += 256) start[i] -= hist[i];  // exclusive
  __syncthreads();
  for (int i = t; i < 512; i += 256) cur[i] = start[i];
  __syncthreads();

#pragma unroll
  for (int k = 0; k < 16; ++k) {
    if (dreg[k] >= 0) {
      int d = dreg[k] >> 8;
      int p = atomicAdd(&cur[d], 1);
      lp[p]  = ((uint)sreg[k] << 8) | ((uint)dreg[k] & 255u);
      bid[p] = (ushort)d;
    }
  }
  __syncthreads();

  for (int i = t; i < NB; i += 256)
    gbase[i] = hist[i] ? atomicAdd(&bcur[i], hist[i]) : 0;
  __syncthreads();

  for (int p = t; p < cnt; p += 256) {
    int d = bid[p];
    int o = gbase[d] + (p - start[d]);
    if (o < BKT_CAP) pairs[(size_t)d * BKT_CAP + o] = lp[p];
  }
}

// ----- CSR build, pass B: per-bucket node sort; emits csr + ro/re + dinv -----

__global__ __launch_bounds__(256) void k_bucketB(const uint* __restrict__ pairs,
                                                 const int* __restrict__ bcur,
                                                 int* __restrict__ csr,
                                                 int* __restrict__ ro,
                                                 int* __restrict__ re,
                                                 float* __restrict__ dinv,
                                                 int N) {
  __shared__ int hist[256];
  __shared__ int cur[256];
  __shared__ int lout[BKT_CAP];    // 24 KB
  __shared__ uint lp[BKT_CAP];     // 24 KB
  int b = blockIdx.x, t = threadIdx.x;
  size_t p0 = (size_t)b * BKT_CAP;
  int cnt = bcur[b]; if (cnt > BKT_CAP) cnt = BKT_CAP;

  hist[t] = 0;
  __syncthreads();
  for (int k = t; k < cnt; k += 256) {
    uint pr = pairs[p0 + k];
    lp[k] = pr;
    atomicAdd(&hist[pr & 255u], 1);
  }
  __syncthreads();

  int v = hist[t];
  cur[t] = v; __syncthreads();
  for (int o = 1; o < 256; o <<= 1) {
    int a = (t >= o) ? cur[t - o] : 0;
    __syncthreads();
    cur[t] += a;
    __syncthreads();
  }
  int excl = cur[t] - v;
  int node = (b << 8) + t;
  if (node < N) {
    ro[node] = (int)p0 + excl;
    re[node] = (int)p0 + excl + v;
    dinv[node] = rsqrtf((float)(v + 1));  // +1 self-loop
  }
  __syncthreads();
  cur[t] = excl;
  __syncthreads();

  for (int k = t; k < cnt; k += 256) {
    uint pr = lp[k];
    int p = atomicAdd(&cur[(int)(pr & 255u)], 1);
    lout[p] = (int)(pr >> 8);
  }
  __syncthreads();
  for (int k = t; k < cnt; k += 256) csr[p0 + k] = lout[k];
}

// ------------- weight repack into MFMA B-fragment order (bf16), fused --------

__device__ inline void pack_one(int idx, const float* __restrict__ W,
                                ushort* __restrict__ Wp, int K, int Ncols) {
  int ksn = K >> 5;
  int l  = idx & 63;
  int ks = (idx >> 6) % ksn;
  int ct = idx / (64 * ksn);
  int col = ct * 16 + (l & 15);
  int kb  = ks * 32 + (l >> 4) * 8;
  short8_t v;
#pragma unroll
  for (int r = 0; r < 8; ++r)
    v[r] = (short)f2bf(W[(size_t)(kb + r) * Ncols + col]);
  *(short8_t*)&Wp[(size_t)idx * 8] = v;
}

__global__ __launch_bounds__(256) void k_packall(const float* __restrict__ Wg,
                                                 const float* __restrict__ W1,
                                                 const float* __restrict__ W2,
                                                 ushort* __restrict__ Wgp,
                                                 ushort* __restrict__ W1p,
                                                 ushort* __restrict__ W2p) {
  int idx = blockIdx.x * 256 + threadIdx.x;
  if (idx < 2048)        pack_one(idx, Wg, Wgp, DN, DN);            // 4*8*64
  else if (idx < 10240)  pack_one(idx - 2048, W1, W1p, DN, H1N);    // 4*32*64
  else if (idx < 26624)  pack_one(idx - 10240, W2, W2p, H1N, H2N);  // 16*16*64
}

// ------ GEMM1: hs = (x @ W_gcn) * dinv[row], SLICE-MAJOR [8][N][16] ----------
// so each XCD's k_agg gather working set is a contiguous 3.2 MB (fits 4MB L2).

__global__ __launch_bounds__(256, 4) void k_gemm1(const float* __restrict__ x,
                                                  const ushort* __restrict__ Wgp,
                                                  const float* __restrict__ dinv,
                                                  ushort* __restrict__ hs, int N) {
  __shared__ ushort xT[64 * 128];  // bf16, XOR-swizzled, 16 KB
  int t = threadIdx.x;
  int row0 = blockIdx.x * 64;

#pragma unroll
  for (int i = 0; i < 4; ++i) {
    int c = t + 256 * i;
    int r = c >> 4, d0 = (c & 15) * 8;
    int gr = row0 + r;
    float4 v0 = {0,0,0,0}, v1 = {0,0,0,0};
    if (gr < N) {
      v0 = *(const float4*)(x + (size_t)gr * DN + d0);
      v1 = *(const float4*)(x + (size_t)gr * DN + d0 + 4);
    }
    short8_t p;
    p[0]=(short)f2bf(v0.x); p[1]=(short)f2bf(v0.y); p[2]=(short)f2bf(v0.z); p[3]=(short)f2bf(v0.w);
    p[4]=(short)f2bf(v1.x); p[5]=(short)f2bf(v1.y); p[6]=(short)f2bf(v1.z); p[7]=(short)f2bf(v1.w);
    *(short8_t*)((char*)xT + r * 256 + ((d0 * 2) ^ ((r & 7) << 4))) = p;
  }
  __syncthreads();

  int w = t >> 6, l = t & 63;
  int lr = l & 15, lk = l >> 4;
  const short8_t* pbg = (const short8_t*)Wgp;

  f32x4 acc[4][2];
#pragma unroll
  for (int mf = 0; mf < 4; ++mf)
#pragma unroll
    for (int n = 0; n < 2; ++n) acc[mf][n] = (f32x4){0.f,0.f,0.f,0.f};

  auto g_load = [&](short8_t (&bb)[2], int ks) {
#pragma unroll
    for (int n = 0; n < 2; ++n)
      bb[n] = pbg[((w * 2 + n) * 4 + ks) * 64 + l];
  };
  auto g_mfma = [&](short8_t (&bb)[2], int ks) {
    short8_t a[4];
#pragma unroll
    for (int mf = 0; mf < 4; ++mf) {
      int r = mf * 16 + lr;
      a[mf] = *(const short8_t*)((const char*)xT + r * 256 + ((ks * 64 + lk * 16) ^ ((r & 7) << 4)));
    }
#pragma unroll
    for (int mf = 0; mf < 4; ++mf)
#pragma unroll
      for (int n = 0; n < 2; ++n)
        acc[mf][n] = __builtin_amdgcn_mfma_f32_16x16x32_bf16(a[mf], bb[n], acc[mf][n], 0, 0, 0);
  };

  short8_t bA[2], bB[2];
  g_load(bA, 0);
  g_load(bB, 1); g_mfma(bA, 0);
  g_load(bA, 2); g_mfma(bB, 1);
  g_load(bB, 3); g_mfma(bA, 2);
  g_mfma(bB, 3);

  float dv[4][4];
#pragma unroll
  for (int mf = 0; mf < 4; ++mf)
#pragma unroll
    for (int r2 = 0; r2 < 4; ++r2) {
      int gr = row0 + mf * 16 + lk * 4 + r2;
      dv[mf][r2] = (gr < N) ? dinv[gr] : 0.f;
    }
#pragma unroll
  for (int n = 0; n < 2; ++n) {
    int s = w * 2 + n;   // slice index (16 cols per slice)
#pragma unroll
    for (int mf = 0; mf < 4; ++mf)
#pragma unroll
      for (int r2 = 0; r2 < 4; ++r2) {
        int gr = row0 + mf * 16 + lk * 4 + r2;
        if (gr < N)
          hs[((size_t)s * N + gr) * 16 + lr] = f2bf(acc[mf][n][r2] * dv[mf][r2]);
      }
  }
}

// --------- aggregation, XCD dim-sliced v2: slice = blockIdx & 7 --------------
// 128 nodes/block, 2 lanes/node, uint4 (8 dims = 16 B) per lane: same load
// width/count per edge as the dense version, but slice (3.2 MB) is L2-resident.
// Residual x added here (fp32, 64 B/node/slice = one cache line).

__global__ __launch_bounds__(256) void k_agg(const ushort* __restrict__ hs,
                                             const float* __restrict__ x,
                                             const int* __restrict__ csr,
                                             const int* __restrict__ ro,
                                             const int* __restrict__ re,
                                             const float* __restrict__ dinv,
                                             const float* __restrict__ bg,
                                             ushort* __restrict__ aggb, int N) {
  int t = threadIdx.x;
  int slice = blockIdx.x & 7;
  int node = (blockIdx.x >> 3) * 128 + (t >> 1);
  if (node >= N) return;
  int d0 = (t & 1) * 8;   // 8 dims within the 16-dim slice

  const ushort* hss = hs + (size_t)slice * N * 16;
  int beg = ro[node], end = re[node];
  float dn = dinv[node];
  uint4 selfv = *(const uint4*)(hss + (size_t)node * 16 + d0);
  float4 x0 = *(const float4*)(x + (size_t)node * DN + slice * 16 + d0);
  float4 x1 = *(const float4*)(x + (size_t)node * DN + slice * 16 + d0 + 4);
  float4 b0 = *(const float4*)(bg + slice * 16 + d0);
  float4 b1v = *(const float4*)(bg + slice * 16 + d0 + 4);

  float s[8];
#pragma unroll
  for (int i = 0; i < 8; ++i) s[i] = 0.f;

  auto accum = [&](uint4 v) {
    s[0] += asf(v.x << 16); s[1] += asf(v.x & 0xffff0000u);
    s[2] += asf(v.y << 16); s[3] += asf(v.y & 0xffff0000u);
    s[4] += asf(v.z << 16); s[5] += asf(v.z & 0xffff0000u);
    s[6] += asf(v.w << 16); s[7] += asf(v.w & 0xffff0000u);
  };

  int e = beg;
  for (; e + 4 <= end; e += 4) {
    int i0 = csr[e], i1 = csr[e + 1], i2 = csr[e + 2], i3 = csr[e + 3];
    uint4 v0 = *(const uint4*)(hss + (size_t)i0 * 16 + d0);
    uint4 v1 = *(const uint4*)(hss + (size_t)i1 * 16 + d0);
    uint4 v2 = *(const uint4*)(hss + (size_t)i2 * 16 + d0);
    uint4 v3 = *(const uint4*)(hss + (size_t)i3 * 16 + d0);
    accum(v0); accum(v1); accum(v2); accum(v3);
  }
  if (e + 2 <= end) {
    int i0 = csr[e], i1 = csr[e + 1];
    uint4 v0 = *(const uint4*)(hss + (size_t)i0 * 16 + d0);
    uint4 v1 = *(const uint4*)(hss + (size_t)i1 * 16 + d0);
    accum(v0); accum(v1);
    e += 2;
  }
  if (e < end) {
    int i0 = csr[e];
    accum(*(const uint4*)(hss + (size_t)i0 * 16 + d0));
  }
  accum(selfv);  // self-loop (pre-scaled by dinv[node])

  float xv[8] = {x0.x, x0.y, x0.z, x0.w, x1.x, x1.y, x1.z, x1.w};
  float bv[8] = {b0.x, b0.y, b0.z, b0.w, b1v.x, b1v.y, b1v.z, b1v.w};
  uint outp[4];
#pragma unroll
  for (int i = 0; i < 4; ++i) {
    ushort lo = f2bf(fmaxf(s[2*i]   * dn + bv[2*i],   0.f) + xv[2*i]);
    ushort hi = f2bf(fmaxf(s[2*i+1] * dn + bv[2*i+1], 0.f) + xv[2*i+1]);
    outp[i] = (uint)lo | ((uint)hi << 16);
  }
  *(uint4*)(aggb + ((size_t)slice * N + node) * 16 + d0) = *(uint4*)outp;
}

// ------------- fused MFMA MLP: out = relu(relu(a@W1+b1)@W2+b2)@W3+b3 ---------
// aggb slice-major. 64 rows/block, 512 thr / 8 waves, col-split 8-way,
// 80 KB LDS -> 2 blocks/CU. Stage-1 3-buffer, stage-2 4-buffer 3-deep prefetch.

__global__ __launch_bounds__(512, 2) void k_mlp(const ushort* __restrict__ aggb,
                                                const ushort* __restrict__ W1p,
                                                const float* __restrict__ b1,
                                                const ushort* __restrict__ W2p,
                                                const float* __restrict__ b2,
                                                const float* __restrict__ W3,
                                                const float* __restrict__ b3,
                                                float* __restrict__ out, int N) {
  __shared__ ushort aT[64 * 128];   // 16 KB (reused as pf[8][64] floats later)
  __shared__ ushort t1[64 * 512];   // 64 KB
  int t = threadIdx.x;
  int row0 = blockIdx.x * 64;

#pragma unroll
  for (int i = 0; i < 2; ++i) {
    int u = t + 512 * i;          // 0..1023 chunks of 8 bf16
    int slice = u >> 7;           // 128 chunks per slice
    int v = u & 127;
    int r = v >> 1, half = v & 1;
    int gr = row0 + r;
    uint4 val = {0, 0, 0, 0};
    if (gr < N) val = *(const uint4*)(aggb + ((size_t)slice * N + gr) * 16 + half * 8);
    int d0 = slice * 16 + half * 8;
    *(uint4*)((char*)aT + r * 256 + ((d0 * 2) ^ ((r & 7) << 4))) = val;
  }
  __syncthreads();

  int w = t >> 6, l = t & 63;
  int lr = l & 15, lk = l >> 4;

  // ---- stage 1: t1[:, w*64:(w+1)*64) = relu(a @ W1 + b1) ----
  const short8_t* pb1 = (const short8_t*)W1p;
  f32x4 acc1[4][4];
#pragma unroll
  for (int mf = 0; mf < 4; ++mf)
#pragma unroll
    for (int n = 0; n < 4; ++n) acc1[mf][n] = (f32x4){0.f,0.f,0.f,0.f};

  auto s1_load = [&](short8_t (&bb)[4], int ks) {
#pragma unroll
    for (int n = 0; n < 4; ++n)
      bb[n] = pb1[((w * 4 + n) * 4 + ks) * 64 + l];
  };
  auto s1_mfma = [&](short8_t (&bb)[4], int ks) {
    short8_t a[4];
#pragma unroll
    for (int mf = 0; mf < 4; ++mf) {
      int r = mf * 16 + lr;
      a[mf] = *(const short8_t*)((const char*)aT + r * 256 + ((ks * 64 + lk * 16) ^ ((r & 7) << 4)));
    }
#pragma unroll
    for (int mf = 0; mf < 4; ++mf)
#pragma unroll
      for (int n = 0; n < 4; ++n)
        acc1[mf][n] = __builtin_amdgcn_mfma_f32_16x16x32_bf16(a[mf], bb[n], acc1[mf][n], 0, 0, 0);
  };

  {
    short8_t bA[4], bB[4], bC[4];
    s1_load(bA, 0); s1_load(bB, 1); s1_load(bC, 2);
    s1_mfma(bA, 0); s1_load(bA, 3);
    s1_mfma(bB, 1);
    s1_mfma(bC, 2);
    s1_mfma(bA, 3);
  }

#pragma unroll
  for (int n = 0; n < 4; ++n) {
    int col = (w * 4 + n) * 16 + lr;
    float bb = b1[col];
#pragma unroll
    for (int mf = 0; mf < 4; ++mf)
#pragma unroll
      for (int r2 = 0; r2 < 4; ++r2) {
        int rr = mf * 16 + lk * 4 + r2;
        *(ushort*)((char*)t1 + rr * 1024 + ((col * 2) ^ ((rr & 7) << 4))) =
            f2bf(fmaxf(acc1[mf][n][r2] + bb, 0.f));
      }
  }
  __syncthreads();

  // ---- stage 2: c2[:, w*32:(w+1)*32) = t1 @ W2, K=512, 3-deep prefetch ----
  const short8_t* pb2 = (const short8_t*)W2p;
  f32x4 acc2[4][2];
#pragma unroll
  for (int mf = 0; mf < 4; ++mf)
#pragma unroll
    for (int n = 0; n < 2; ++n) acc2[mf][n] = (f32x4){0.f,0.f,0.f,0.f};

  auto s2_load = [&](short8_t (&bb)[4], int p) {   // pair p: ks = 2p, 2p+1
#pragma unroll
    for (int n = 0; n < 2; ++n) {
      bb[n]     = pb2[((w * 2 + n) * 16 + 2 * p)     * 64 + l];
      bb[2 + n] = pb2[((w * 2 + n) * 16 + 2 * p + 1) * 64 + l];
    }
  };
  auto s2_mfma = [&](short8_t (&bb)[4], int p) {
#pragma unroll
    for (int h = 0; h < 2; ++h) {
      int ks = 2 * p + h;
      short8_t a[4];
#pragma unroll
      for (int mf = 0; mf < 4; ++mf) {
        int r = mf * 16 + lr;
        a[mf] = *(const short8_t*)((const char*)t1 + r * 1024 + ((ks * 64 + lk * 16) ^ ((r & 7) << 4)));
      }
#pragma unroll
      for (int mf = 0; mf < 4; ++mf)
#pragma unroll
        for (int n = 0; n < 2; ++n)
          acc2[mf][n] = __builtin_amdgcn_mfma_f32_16x16x32_bf16(a[mf], bb[2 * h + n], acc2[mf][n], 0, 0, 0);
    }
  };

  {
    short8_t c0[4], c1[4], c2b[4], c3[4];
    s2_load(c0, 0); s2_load(c1, 1); s2_load(c2b, 2);
    s2_load(c3, 3); s2_mfma(c0, 0);
    s2_load(c0, 4); s2_mfma(c1, 1);
    s2_load(c1, 5); s2_mfma(c2b, 2);
    s2_load(c2b, 6); s2_mfma(c3, 3);
    s2_load(c3, 7); s2_mfma(c0, 4);
    s2_mfma(c1, 5);
    s2_mfma(c2b, 6);
    s2_mfma(c3, 7);
  }

  // ---- stage 3 folded: po = relu(c2 + b2) @ W3 (partial over own 32 cols) ----
  float po[4][4];
#pragma unroll
  for (int mf = 0; mf < 4; ++mf)
#pragma unroll
    for (int r2 = 0; r2 < 4; ++r2) po[mf][r2] = 0.f;
#pragma unroll
  for (int n = 0; n < 2; ++n) {
    int col = (w * 2 + n) * 16 + lr;
    float bb = b2[col];
    float w3 = W3[col];
#pragma unroll
    for (int mf = 0; mf < 4; ++mf)
#pragma unroll
      for (int r2 = 0; r2 < 4; ++r2)
        po[mf][r2] += fmaxf(acc2[mf][n][r2] + bb, 0.f) * w3;
  }
#pragma unroll
  for (int mf = 0; mf < 4; ++mf)
#pragma unroll
    for (int r2 = 0; r2 < 4; ++r2) {
      float v = po[mf][r2];
      v += __shfl_xor(v, 1, 64);
      v += __shfl_xor(v, 2, 64);
      v += __shfl_xor(v, 4, 64);
      v += __shfl_xor(v, 8, 64);
      po[mf][r2] = v;
    }
  float* pf = (float*)aT;   // aT reads all finished before stage-1->2 barrier
  if (lr == 0) {
#pragma unroll
    for (int mf = 0; mf < 4; ++mf)
#pragma unroll
      for (int r2 = 0; r2 < 4; ++r2)
        pf[w * 64 + mf * 16 + lk * 4 + r2] = po[mf][r2];
  }
  __syncthreads();
  if (t < 64) {
    int gr = row0 + t;
    if (gr < N) {
      float s = b3[0];
#pragma unroll
      for (int ww = 0; ww < 8; ++ww) s += pf[ww * 64 + t];
      out[gr] = s;
    }
  }
}

// ------------------------------- launcher ------------------------------------

extern "C" void kernel_launch(void* const* d_in, const int* in_sizes, int n_in,
                              void* d_out, int out_size, void* d_ws, size_t ws_size,
                              hipStream_t stream) {
  const float* x  = (const float*)d_in[0];
  const int*   ei = (const int*)d_in[1];
  const float* Wg = (const float*)d_in[2];
  const float* bg = (const float*)d_in[3];
  const float* W1 = (const float*)d_in[4];
  const float* b1 = (const float*)d_in[5];
  const float* W2 = (const float*)d_in[6];
  const float* b2 = (const float*)d_in[7];
  const float* W3 = (const float*)d_in[8];
  const float* b3 = (const float*)d_in[9];
  float* out = (float*)d_out;

  const int N = in_sizes[0] / DN;
  const int E = in_sizes[1] / 2;
  const int NB = (N + 255) >> 8;

  char* ws = (char*)d_ws;
  size_t off = 0;
  auto alloc = [&](size_t bytes) -> void* {
    void* p = ws + off;
    off = (off + bytes + 255) & ~(size_t)255;
    return p;
  };
  int*    bcur   = (int*)alloc((size_t)NB * 4);
  int*    ro     = (int*)alloc((size_t)N * 4);
  int*    re     = (int*)alloc((size_t)N * 4);
  float*  dinv   = (float*)alloc((size_t)N * 4);
  int*    csr    = (int*)alloc((size_t)NB * BKT_CAP * 4);
  uint*   pairs  = (uint*)alloc((size_t)NB * BKT_CAP * 4);
  ushort* hsb    = (ushort*)alloc((size_t)N * DN * 2);
  ushort* aggb   = (ushort*)alloc((size_t)N * DN * 2);
  ushort* Wgp    = (ushort*)alloc((size_t)DN * DN * 2);
  ushort* W1p    = (ushort*)alloc((size_t)DN * H1N * 2);
  ushort* W2p    = (ushort*)alloc((size_t)H1N * H2N * 2);
  (void)ws_size; (void)n_in; (void)out_size;

  hipMemsetAsync(bcur, 0, (size_t)NB * 4, stream);

  int nTiles = (E + TILE_A - 1) / TILE_A;
  k_bucketA<<<nTiles, 256, 0, stream>>>(ei, bcur, pairs, E, NB);
  k_bucketB<<<NB, 256, 0, stream>>>(pairs, bcur, csr, ro, re, dinv, N);

  k_packall<<<104, 256, 0, stream>>>(Wg, W1, W2, Wgp, W1p, W2p);

  int nb64 = (N + 63) / 64;
  k_gemm1<<<nb64, 256, 0, stream>>>(x, Wgp, dinv, hsb, N);
  int nb128 = (N + 127) / 128;
  k_agg<<<nb128 * 8, 256, 0, stream>>>(hsb, x, csr, ro, re, dinv, bg, aggb, N);
  k_mlp<<<nb64, 512, 0, stream>>>(aggb, W1p, b1, W2p, b2, W3, b3, out, N);
}

// Round 13
// 188.825 us; speedup vs baseline: 1.1782x; 1.1782x over previous
//
#include <hip/hip_runtime.h>

#define DN  128
#define H1N 512
#define H2N 256
#define TILE_A 4096
#define BKT_CAP 6144   // fixed bucket capacity: mean 4096, +32 sigma

typedef __attribute__((ext_vector_type(8))) short short8_t;   // 8 bf16
typedef __attribute__((ext_vector_type(4))) float f32x4;      // MFMA acc

__device__ inline ushort f2bf(float f) {
  union { float f; unsigned u; } v; v.f = f;
  unsigned r = v.u + 0x7FFF + ((v.u >> 16) & 1);   // RNE
  return (ushort)(r >> 16);
}
__device__ inline float asf(unsigned u) {
  union { unsigned u; float f; } v; v.u = u;
  return v.f;
}

// -------- CSR build, pass A: tile-reorder bucketize into fixed-cap buckets ---

__global__ __launch_bounds__(256) void k_bucketA(const int* __restrict__ ei,
                                                 int* __restrict__ bcur,
                                                 uint* __restrict__ pairs,
                                                 int E, int NB) {
  __shared__ int hist[512];
  __shared__ int start[512];
  __shared__ int cur[512];
  __shared__ int gbase[512];
  __shared__ uint lp[TILE_A];      // 16 KB
  __shared__ ushort bid[TILE_A];   // 8 KB
  int t = threadIdx.x;
  int base = blockIdx.x * TILE_A;
  int cnt = E - base; if (cnt > TILE_A) cnt = TILE_A;

  for (int i = t; i < 512; i += 256) hist[i] = 0;
  __syncthreads();

  int sreg[16], dreg[16];
#pragma unroll
  for (int k = 0; k < 16; ++k) {
    int idx = t + 256 * k;
    bool v = idx < cnt;
    sreg[k] = v ? ei[base + idx] : 0;
    dreg[k] = v ? ei[E + base + idx] : -1;
    if (v) atomicAdd(&hist[dreg[k] >> 8], 1);
  }
  __syncthreads();

  for (int i = t; i < 512; i += 256) start[i] = hist[i];
  __syncthreads();
  for (int o = 1; o < 512; o <<= 1) {
    int i0 = t, i1 = t + 256;
    int v0 = (i0 >= o) ? start[i0 - o] : 0;
    int v1 = (i1 >= o) ? start[i1 - o] : 0;
    __syncthreads();
    start[i0] += v0;
    start[i1] += v1;
    __syncthreads();
  }
  for (int i = t; i < 512; i += 256) start[i] -= hist[i];  // exclusive
  __syncthreads();
  for (int i = t; i < 512; i += 256) cur[i] = start[i];
  __syncthreads();

#pragma unroll
  for (int k = 0; k < 16; ++k) {
    if (dreg[k] >= 0) {
      int d = dreg[k] >> 8;
      int p = atomicAdd(&cur[d], 1);
      lp[p]  = ((uint)sreg[k] << 8) | ((uint)dreg[k] & 255u);
      bid[p] = (ushort)d;
    }
  }
  __syncthreads();

  for (int i = t; i < NB; i += 256)
    gbase[i] = hist[i] ? atomicAdd(&bcur[i], hist[i]) : 0;
  __syncthreads();

  for (int p = t; p < cnt; p += 256) {
    int d = bid[p];
    int o = gbase[d] + (p - start[d]);
    if (o < BKT_CAP) pairs[(size_t)d * BKT_CAP + o] = lp[p];
  }
}

// ----- CSR build, pass B: per-bucket node sort; emits csr + ro/re + dinv -----

__global__ __launch_bounds__(256) void k_bucketB(const uint* __restrict__ pairs,
                                                 const int* __restrict__ bcur,
                                                 int* __restrict__ csr,
                                                 int* __restrict__ ro,
                                                 int* __restrict__ re,
                                                 float* __restrict__ dinv,
                                                 int N) {
  __shared__ int hist[256];
  __shared__ int cur[256];
  __shared__ int lout[BKT_CAP];    // 24 KB
  __shared__ uint lp[BKT_CAP];     // 24 KB
  int b = blockIdx.x, t = threadIdx.x;
  size_t p0 = (size_t)b * BKT_CAP;
  int cnt = bcur[b]; if (cnt > BKT_CAP) cnt = BKT_CAP;

  hist[t] = 0;
  __syncthreads();
  for (int k = t; k < cnt; k += 256) {
    uint pr = pairs[p0 + k];
    lp[k] = pr;
    atomicAdd(&hist[pr & 255u], 1);
  }
  __syncthreads();

  int v = hist[t];
  cur[t] = v; __syncthreads();
  for (int o = 1; o < 256; o <<= 1) {
    int a = (t >= o) ? cur[t - o] : 0;
    __syncthreads();
    cur[t] += a;
    __syncthreads();
  }
  int excl = cur[t] - v;
  int node = (b << 8) + t;
  if (node < N) {
    ro[node] = (int)p0 + excl;
    re[node] = (int)p0 + excl + v;
    dinv[node] = rsqrtf((float)(v + 1));  // +1 self-loop
  }
  __syncthreads();
  cur[t] = excl;
  __syncthreads();

  for (int k = t; k < cnt; k += 256) {
    uint pr = lp[k];
    int p = atomicAdd(&cur[(int)(pr & 255u)], 1);
    lout[p] = (int)(pr >> 8);
  }
  __syncthreads();
  for (int k = t; k < cnt; k += 256) csr[p0 + k] = lout[k];
}

// ------------- weight repack into MFMA fragment order (bf16), fused ----------
// Layout serves BOTH roles: as B-frag (k, col) and as A-frag for the swapped
// product (row=col-of-W, k) — identical lane->element structure.

__device__ inline void pack_one(int idx, const float* __restrict__ W,
                                ushort* __restrict__ Wp, int K, int Ncols) {
  int ksn = K >> 5;
  int l  = idx & 63;
  int ks = (idx >> 6) % ksn;
  int ct = idx / (64 * ksn);
  int col = ct * 16 + (l & 15);
  int kb  = ks * 32 + (l >> 4) * 8;
  short8_t v;
#pragma unroll
  for (int r = 0; r < 8; ++r)
    v[r] = (short)f2bf(W[(size_t)(kb + r) * Ncols + col]);
  *(short8_t*)&Wp[(size_t)idx * 8] = v;
}

__global__ __launch_bounds__(256) void k_packall(const float* __restrict__ Wg,
                                                 const float* __restrict__ W1,
                                                 const float* __restrict__ W2,
                                                 ushort* __restrict__ Wgp,
                                                 ushort* __restrict__ W1p,
                                                 ushort* __restrict__ W2p) {
  int idx = blockIdx.x * 256 + threadIdx.x;
  if (idx < 2048)        pack_one(idx, Wg, Wgp, DN, DN);            // 4*8*64
  else if (idx < 10240)  pack_one(idx - 2048, W1, W1p, DN, H1N);    // 4*32*64
  else if (idx < 26624)  pack_one(idx - 10240, W2, W2p, H1N, H2N);  // 16*16*64
}

// ---------------- GEMM1: hs = (x @ W_gcn) * dinv[row]  (bf16, row-major) -----

__global__ __launch_bounds__(256, 4) void k_gemm1(const float* __restrict__ x,
                                                  const ushort* __restrict__ Wgp,
                                                  const float* __restrict__ dinv,
                                                  ushort* __restrict__ hs, int N) {
  __shared__ ushort xT[64 * 128];  // bf16, XOR-swizzled, 16 KB
  int t = threadIdx.x;
  int row0 = blockIdx.x * 64;

#pragma unroll
  for (int i = 0; i < 4; ++i) {
    int c = t + 256 * i;
    int r = c >> 4, d0 = (c & 15) * 8;
    int gr = row0 + r;
    float4 v0 = {0,0,0,0}, v1 = {0,0,0,0};
    if (gr < N) {
      v0 = *(const float4*)(x + (size_t)gr * DN + d0);
      v1 = *(const float4*)(x + (size_t)gr * DN + d0 + 4);
    }
    short8_t p;
    p[0]=(short)f2bf(v0.x); p[1]=(short)f2bf(v0.y); p[2]=(short)f2bf(v0.z); p[3]=(short)f2bf(v0.w);
    p[4]=(short)f2bf(v1.x); p[5]=(short)f2bf(v1.y); p[6]=(short)f2bf(v1.z); p[7]=(short)f2bf(v1.w);
    *(short8_t*)((char*)xT + r * 256 + ((d0 * 2) ^ ((r & 7) << 4))) = p;
  }
  __syncthreads();

  int w = t >> 6, l = t & 63;
  int lr = l & 15, lk = l >> 4;
  const short8_t* pbg = (const short8_t*)Wgp;

  f32x4 acc[4][2];
#pragma unroll
  for (int mf = 0; mf < 4; ++mf)
#pragma unroll
    for (int n = 0; n < 2; ++n) acc[mf][n] = (f32x4){0.f,0.f,0.f,0.f};

  auto g_load = [&](short8_t (&bb)[2], int ks) {
#pragma unroll
    for (int n = 0; n < 2; ++n)
      bb[n] = pbg[((w * 2 + n) * 4 + ks) * 64 + l];
  };
  auto g_mfma = [&](short8_t (&bb)[2], int ks) {
    short8_t a[4];
#pragma unroll
    for (int mf = 0; mf < 4; ++mf) {
      int r = mf * 16 + lr;
      a[mf] = *(const short8_t*)((const char*)xT + r * 256 + ((ks * 64 + lk * 16) ^ ((r & 7) << 4)));
    }
#pragma unroll
    for (int mf = 0; mf < 4; ++mf)
#pragma unroll
      for (int n = 0; n < 2; ++n)
        acc[mf][n] = __builtin_amdgcn_mfma_f32_16x16x32_bf16(a[mf], bb[n], acc[mf][n], 0, 0, 0);
  };

  short8_t bA[2], bB[2];
  g_load(bA, 0);
  g_load(bB, 1); g_mfma(bA, 0);
  g_load(bA, 2); g_mfma(bB, 1);
  g_load(bB, 3); g_mfma(bA, 2);
  g_mfma(bB, 3);

  float dv[4][4];
#pragma unroll
  for (int mf = 0; mf < 4; ++mf)
#pragma unroll
    for (int r2 = 0; r2 < 4; ++r2) {
      int gr = row0 + mf * 16 + lk * 4 + r2;
      dv[mf][r2] = (gr < N) ? dinv[gr] : 0.f;
    }
#pragma unroll
  for (int n = 0; n < 2; ++n) {
    int col = (w * 2 + n) * 16 + lr;
#pragma unroll
    for (int mf = 0; mf < 4; ++mf)
#pragma unroll
      for (int r2 = 0; r2 < 4; ++r2) {
        int gr = row0 + mf * 16 + lk * 4 + r2;
        if (gr < N) hs[(size_t)gr * DN + col] = f2bf(acc[mf][n][r2] * dv[mf][r2]);
      }
  }
}

// --------- aggregation: agg = bf16(relu(dinv*(sum+self) + b) + x) ------------
// 16 nodes/block, 16 lanes/node, 8 dims (uint4) per lane. 4-deep gather unroll.

__global__ __launch_bounds__(256) void k_agg(const ushort* __restrict__ hs,
                                             const float* __restrict__ x,
                                             const int* __restrict__ csr,
                                             const int* __restrict__ ro,
                                             const int* __restrict__ re,
                                             const float* __restrict__ dinv,
                                             const float* __restrict__ bg,
                                             ushort* __restrict__ aggb, int N) {
  int t = threadIdx.x;
  int node = blockIdx.x * 16 + (t >> 4);
  if (node >= N) return;
  int d0 = (t & 15) * 8;

  int beg = ro[node], end = re[node];
  float dn = dinv[node];
  uint4 selfv = *(const uint4*)(hs + (size_t)node * DN + d0);
  float4 x0 = *(const float4*)(x + (size_t)node * DN + d0);
  float4 x1 = *(const float4*)(x + (size_t)node * DN + d0 + 4);
  float4 b0 = *(const float4*)(bg + d0);
  float4 b1v = *(const float4*)(bg + d0 + 4);

  float s[8];
#pragma unroll
  for (int i = 0; i < 8; ++i) s[i] = 0.f;

  auto accum = [&](uint4 v) {
    s[0] += asf(v.x << 16); s[1] += asf(v.x & 0xffff0000u);
    s[2] += asf(v.y << 16); s[3] += asf(v.y & 0xffff0000u);
    s[4] += asf(v.z << 16); s[5] += asf(v.z & 0xffff0000u);
    s[6] += asf(v.w << 16); s[7] += asf(v.w & 0xffff0000u);
  };

  int e = beg;
  for (; e + 4 <= end; e += 4) {
    int i0 = csr[e], i1 = csr[e + 1], i2 = csr[e + 2], i3 = csr[e + 3];
    uint4 v0 = *(const uint4*)(hs + (size_t)i0 * DN + d0);
    uint4 v1 = *(const uint4*)(hs + (size_t)i1 * DN + d0);
    uint4 v2 = *(const uint4*)(hs + (size_t)i2 * DN + d0);
    uint4 v3 = *(const uint4*)(hs + (size_t)i3 * DN + d0);
    accum(v0); accum(v1); accum(v2); accum(v3);
  }
  if (e + 2 <= end) {
    int i0 = csr[e], i1 = csr[e + 1];
    uint4 v0 = *(const uint4*)(hs + (size_t)i0 * DN + d0);
    uint4 v1 = *(const uint4*)(hs + (size_t)i1 * DN + d0);
    accum(v0); accum(v1);
    e += 2;
  }
  if (e < end) {
    int i0 = csr[e];
    accum(*(const uint4*)(hs + (size_t)i0 * DN + d0));
  }
  accum(selfv);  // self-loop (pre-scaled by dinv[node])

  float xv[8] = {x0.x, x0.y, x0.z, x0.w, x1.x, x1.y, x1.z, x1.w};
  float bv[8] = {b0.x, b0.y, b0.z, b0.w, b1v.x, b1v.y, b1v.z, b1v.w};
  uint outp[4];
#pragma unroll
  for (int i = 0; i < 4; ++i) {
    ushort lo = f2bf(fmaxf(s[2*i]   * dn + bv[2*i],   0.f) + xv[2*i]);
    ushort hi = f2bf(fmaxf(s[2*i+1] * dn + bv[2*i+1], 0.f) + xv[2*i+1]);
    outp[i] = (uint)lo | ((uint)hi << 16);
  }
  *(uint4*)(aggb + (size_t)node * DN + d0) = *(uint4*)outp;
}

// ------------- fused MFMA MLP (SWAPPED operands): D' = W^T-frag x act-frag ---
// 64 rows/block, 512 thr / 8 waves, col-split 8-way, 80 KB LDS -> 2 blocks/CU.
// Swapped mfma puts col=node in D: t1 writes become ushort4 (8B) per lane,
// stage-3 reduce needs only 2 shuffles.

__global__ __launch_bounds__(512, 2) void k_mlp(const ushort* __restrict__ aggb,
                                                const ushort* __restrict__ W1p,
                                                const float* __restrict__ b1,
                                                const ushort* __restrict__ W2p,
                                                const float* __restrict__ b2,
                                                const float* __restrict__ W3,
                                                const float* __restrict__ b3,
                                                float* __restrict__ out, int N) {
  __shared__ ushort aT[64 * 128];   // 16 KB (reused as pf[8][64] floats later)
  __shared__ ushort t1[64 * 512];   // 64 KB
  int t = threadIdx.x;
  int row0 = blockIdx.x * 64;

#pragma unroll
  for (int i = 0; i < 2; ++i) {
    int c = t + 512 * i;
    int r = c >> 4;
    int cb = (c & 15) * 16;
    int gr = row0 + r;
    uint4 v = {0, 0, 0, 0};
    if (gr < N) v = *(const uint4*)(aggb + (size_t)gr * DN + (c & 15) * 8);
    *(uint4*)((char*)aT + r * 256 + (cb ^ ((r & 7) << 4))) = v;
  }
  __syncthreads();

  int w = t >> 6, l = t & 63;
  int lr = l & 15, lk = l >> 4;

  // ---- stage 1 (swapped): acc1[n][mf] = W1'[cols w*64..] x a  ----
  const short8_t* pb1 = (const short8_t*)W1p;
  f32x4 acc1[4][4];   // [n: w1col-tile][mf: node-tile]
#pragma unroll
  for (int n = 0; n < 4; ++n)
#pragma unroll
    for (int mf = 0; mf < 4; ++mf) acc1[n][mf] = (f32x4){0.f,0.f,0.f,0.f};

  auto s1_load = [&](short8_t (&bb)[4], int ks) {
#pragma unroll
    for (int n = 0; n < 4; ++n)
      bb[n] = pb1[((w * 4 + n) * 4 + ks) * 64 + l];
  };
  auto s1_mfma = [&](short8_t (&bb)[4], int ks) {
    short8_t aF[4];
#pragma unroll
    for (int mf = 0; mf < 4; ++mf) {
      int r = mf * 16 + lr;
      aF[mf] = *(const short8_t*)((const char*)aT + r * 256 + ((ks * 64 + lk * 16) ^ ((r & 7) << 4)));
    }
#pragma unroll
    for (int n = 0; n < 4; ++n)
#pragma unroll
      for (int mf = 0; mf < 4; ++mf)
        acc1[n][mf] = __builtin_amdgcn_mfma_f32_16x16x32_bf16(bb[n], aF[mf], acc1[n][mf], 0, 0, 0);
  };

  {
    short8_t bA[4], bB[4];
    s1_load(bA, 0);
    s1_load(bB, 1); s1_mfma(bA, 0);
    s1_load(bA, 2); s1_mfma(bB, 1);
    s1_load(bB, 3); s1_mfma(bA, 2);
    s1_mfma(bB, 3);
  }

  // epilogue: lane holds node = mf*16+lr, w1cols (w*4+n)*16 + lk*4 + r2 (4 consecutive)
#pragma unroll
  for (int n = 0; n < 4; ++n) {
    f32x4 b1v = *(const f32x4*)&b1[(w * 4 + n) * 16 + lk * 4];
#pragma unroll
    for (int mf = 0; mf < 4; ++mf) {
      int rr = mf * 16 + lr;
      ushort4 pk;
      pk.x = f2bf(fmaxf(acc1[n][mf][0] + b1v[0], 0.f));
      pk.y = f2bf(fmaxf(acc1[n][mf][1] + b1v[1], 0.f));
      pk.z = f2bf(fmaxf(acc1[n][mf][2] + b1v[2], 0.f));
      pk.w = f2bf(fmaxf(acc1[n][mf][3] + b1v[3], 0.f));
      int cb2 = ((w * 4 + n) * 32 + lk * 8) ^ ((rr & 7) << 4);
      *(ushort4*)((char*)t1 + rr * 1024 + cb2) = pk;
    }
  }
  __syncthreads();

  // ---- stage 2 (swapped): acc2[n][mf] = W2'[cols w*32..] x t1, K=512 ----
  const short8_t* pb2 = (const short8_t*)W2p;
  f32x4 acc2[2][4];   // [n: w2col-tile][mf: node-tile]
#pragma unroll
  for (int n = 0; n < 2; ++n)
#pragma unroll
    for (int mf = 0; mf < 4; ++mf) acc2[n][mf] = (f32x4){0.f,0.f,0.f,0.f};

  auto s2_load = [&](short8_t (&bb)[2], int ks) {
#pragma unroll
    for (int n = 0; n < 2; ++n)
      bb[n] = pb2[((w * 2 + n) * 16 + ks) * 64 + l];
  };
  auto s2_mfma = [&](short8_t (&bb)[2], int ks) {
    short8_t tF[4];
#pragma unroll
    for (int mf = 0; mf < 4; ++mf) {
      int r = mf * 16 + lr;
      tF[mf] = *(const short8_t*)((const char*)t1 + r * 1024 + ((ks * 64 + lk * 16) ^ ((r & 7) << 4)));
    }
#pragma unroll
    for (int n = 0; n < 2; ++n)
#pragma unroll
      for (int mf = 0; mf < 4; ++mf)
        acc2[n][mf] = __builtin_amdgcn_mfma_f32_16x16x32_bf16(bb[n], tF[mf], acc2[n][mf], 0, 0, 0);
  };

  {
    short8_t c0[2], c1[2], c2[2];
    s2_load(c0, 0); s2_load(c1, 1); s2_load(c2, 2);
    s2_mfma(c0, 0);  s2_load(c0, 3);
    s2_mfma(c1, 1);  s2_load(c1, 4);
    s2_mfma(c2, 2);  s2_load(c2, 5);
    s2_mfma(c0, 3);  s2_load(c0, 6);
    s2_mfma(c1, 4);  s2_load(c1, 7);
    s2_mfma(c2, 5);  s2_load(c2, 8);
    s2_mfma(c0, 6);  s2_load(c0, 9);
    s2_mfma(c1, 7);  s2_load(c1, 10);
    s2_mfma(c2, 8);  s2_load(c2, 11);
    s2_mfma(c0, 9);  s2_load(c0, 12);
    s2_mfma(c1, 10); s2_load(c1, 13);
    s2_mfma(c2, 11); s2_load(c2, 14);
    s2_mfma(c0, 12); s2_load(c0, 15);
    s2_mfma(c1, 13);
    s2_mfma(c2, 14);
    s2_mfma(c0, 15);
  }

  // ---- stage 3 folded: lane holds node = mf*16+lr, w2cols (w*2+n)*16+lk*4+r2
  float po[4];
#pragma unroll
  for (int mf = 0; mf < 4; ++mf) po[mf] = 0.f;
#pragma unroll
  for (int n = 0; n < 2; ++n) {
    int colb = (w * 2 + n) * 16 + lk * 4;
    f32x4 b2v = *(const f32x4*)&b2[colb];
    f32x4 w3v = *(const f32x4*)&W3[colb];
#pragma unroll
    for (int mf = 0; mf < 4; ++mf)
#pragma unroll
      for (int r2 = 0; r2 < 4; ++r2)
        po[mf] += fmaxf(acc2[n][mf][r2] + b2v[r2], 0.f) * w3v[r2];
  }
#pragma unroll
  for (int mf = 0; mf < 4; ++mf) {
    float v = po[mf];
    v += __shfl_xor(v, 16, 64);
    v += __shfl_xor(v, 32, 64);
    po[mf] = v;
  }
  float* pf = (float*)aT;   // aT reads all finished before stage-1->2 barrier
  if (lk == 0) {
#pragma unroll
    for (int mf = 0; mf < 4; ++mf)
      pf[w * 64 + mf * 16 + lr] = po[mf];
  }
  __syncthreads();
  if (t < 64) {
    int gr = row0 + t;
    if (gr < N) {
      float s = b3[0];
#pragma unroll
      for (int ww = 0; ww < 8; ++ww) s += pf[ww * 64 + t];
      out[gr] = s;
    }
  }
}

// ------------------------------- launcher ------------------------------------

extern "C" void kernel_launch(void* const* d_in, const int* in_sizes, int n_in,
                              void* d_out, int out_size, void* d_ws, size_t ws_size,
                              hipStream_t stream) {
  const float* x  = (const float*)d_in[0];
  const int*   ei = (const int*)d_in[1];
  const float* Wg = (const float*)d_in[2];
  const float* bg = (const float*)d_in[3];
  const float* W1 = (const float*)d_in[4];
  const float* b1 = (const float*)d_in[5];
  const float* W2 = (const float*)d_in[6];
  const float* b2 = (const float*)d_in[7];
  const float* W3 = (const float*)d_in[8];
  const float* b3 = (const float*)d_in[9];
  float* out = (float*)d_out;

  const int N = in_sizes[0] / DN;
  const int E = in_sizes[1] / 2;
  const int NB = (N + 255) >> 8;

  char* ws = (char*)d_ws;
  size_t off = 0;
  auto alloc = [&](size_t bytes) -> void* {
    void* p = ws + off;
    off = (off + bytes + 255) & ~(size_t)255;
    return p;
  };
  int*    bcur   = (int*)alloc((size_t)NB * 4);
  int*    ro     = (int*)alloc((size_t)N * 4);
  int*    re     = (int*)alloc((size_t)N * 4);
  float*  dinv   = (float*)alloc((size_t)N * 4);
  int*    csr    = (int*)alloc((size_t)NB * BKT_CAP * 4);
  uint*   pairs  = (uint*)alloc((size_t)NB * BKT_CAP * 4);
  ushort* hsb    = (ushort*)alloc((size_t)N * DN * 2);
  ushort* aggb   = (ushort*)alloc((size_t)N * DN * 2);
  ushort* Wgp    = (ushort*)alloc((size_t)DN * DN * 2);
  ushort* W1p    = (ushort*)alloc((size_t)DN * H1N * 2);
  ushort* W2p    = (ushort*)alloc((size_t)H1N * H2N * 2);
  (void)ws_size; (void)n_in; (void)out_size;

  hipMemsetAsync(bcur, 0, (size_t)NB * 4, stream);

  int nTiles = (E + TILE_A - 1) / TILE_A;
  k_bucketA<<<nTiles, 256, 0, stream>>>(ei, bcur, pairs, E, NB);
  k_bucketB<<<NB, 256, 0, stream>>>(pairs, bcur, csr, ro, re, dinv, N);

  k_packall<<<104, 256, 0, stream>>>(Wg, W1, W2, Wgp, W1p, W2p);

  int nb64 = (N + 63) / 64;
  k_gemm1<<<nb64, 256, 0, stream>>>(x, Wgp, dinv, hsb, N);
  k_agg<<<(N + 15) / 16, 256, 0, stream>>>(hsb, x, csr, ro, re, dinv, bg, aggb, N);
  k_mlp<<<nb64, 512, 0, stream>>>(aggb, W1p, b1, W2p, b2, W3, b3, out, N);
}

// Round 14
// 188.283 us; speedup vs baseline: 1.1816x; 1.0029x over previous
//
#include <hip/hip_runtime.h>

#define DN  128
#define H1N 512
#define H2N 256
#define TILE_A 4096
#define BKT_CAP 6144   // fixed bucket capacity: mean 4096, +32 sigma

typedef __attribute__((ext_vector_type(8))) short short8_t;   // 8 bf16
typedef __attribute__((ext_vector_type(4))) float f32x4;      // MFMA acc

__device__ inline ushort f2bf(float f) {
  union { float f; unsigned u; } v; v.f = f;
  unsigned r = v.u + 0x7FFF + ((v.u >> 16) & 1);   // RNE
  return (ushort)(r >> 16);
}
__device__ inline float asf(unsigned u) {
  union { unsigned u; float f; } v; v.u = u;
  return v.f;
}

// -------- CSR build, pass A: tile-reorder bucketize into fixed-cap buckets ---

__global__ __launch_bounds__(256) void k_bucketA(const int* __restrict__ ei,
                                                 int* __restrict__ bcur,
                                                 uint* __restrict__ pairs,
                                                 int E, int NB) {
  __shared__ int hist[512];
  __shared__ int start[512];
  __shared__ int cur[512];
  __shared__ int gbase[512];
  __shared__ uint lp[TILE_A];      // 16 KB
  __shared__ ushort bid[TILE_A];   // 8 KB
  int t = threadIdx.x;
  int base = blockIdx.x * TILE_A;
  int cnt = E - base; if (cnt > TILE_A) cnt = TILE_A;

  for (int i = t; i < 512; i += 256) hist[i] = 0;
  __syncthreads();

  int sreg[16], dreg[16];
#pragma unroll
  for (int k = 0; k < 16; ++k) {
    int idx = t + 256 * k;
    bool v = idx < cnt;
    sreg[k] = v ? ei[base + idx] : 0;
    dreg[k] = v ? ei[E + base + idx] : -1;
    if (v) atomicAdd(&hist[dreg[k] >> 8], 1);
  }
  __syncthreads();

  for (int i = t; i < 512; i += 256) start[i] = hist[i];
  __syncthreads();
  for (int o = 1; o < 512; o <<= 1) {
    int i0 = t, i1 = t + 256;
    int v0 = (i0 >= o) ? start[i0 - o] : 0;
    int v1 = (i1 >= o) ? start[i1 - o] : 0;
    __syncthreads();
    start[i0] += v0;
    start[i1] += v1;
    __syncthreads();
  }
  for (int i = t; i < 512; i += 256) start[i] -= hist[i];  // exclusive
  __syncthreads();
  for (int i = t; i < 512; i += 256) cur[i] = start[i];
  __syncthreads();

#pragma unroll
  for (int k = 0; k < 16; ++k) {
    if (dreg[k] >= 0) {
      int d = dreg[k] >> 8;
      int p = atomicAdd(&cur[d], 1);
      lp[p]  = ((uint)sreg[k] << 8) | ((uint)dreg[k] & 255u);
      bid[p] = (ushort)d;
    }
  }
  __syncthreads();

  for (int i = t; i < NB; i += 256)
    gbase[i] = hist[i] ? atomicAdd(&bcur[i], hist[i]) : 0;
  __syncthreads();

  for (int p = t; p < cnt; p += 256) {
    int d = bid[p];
    int o = gbase[d] + (p - start[d]);
    if (o < BKT_CAP) pairs[(size_t)d * BKT_CAP + o] = lp[p];
  }
}

// ----- CSR build, pass B: per-bucket node sort; emits csr + ro/re + dinv -----

__global__ __launch_bounds__(256) void k_bucketB(const uint* __restrict__ pairs,
                                                 const int* __restrict__ bcur,
                                                 int* __restrict__ csr,
                                                 int* __restrict__ ro,
                                                 int* __restrict__ re,
                                                 float* __restrict__ dinv,
                                                 int N) {
  __shared__ int hist[256];
  __shared__ int cur[256];
  __shared__ int lout[BKT_CAP];    // 24 KB
  __shared__ uint lp[BKT_CAP];     // 24 KB
  int b = blockIdx.x, t = threadIdx.x;
  size_t p0 = (size_t)b * BKT_CAP;
  int cnt = bcur[b]; if (cnt > BKT_CAP) cnt = BKT_CAP;

  hist[t] = 0;
  __syncthreads();
  for (int k = t; k < cnt; k += 256) {
    uint pr = pairs[p0 + k];
    lp[k] = pr;
    atomicAdd(&hist[pr & 255u], 1);
  }
  __syncthreads();

  int v = hist[t];
  cur[t] = v; __syncthreads();
  for (int o = 1; o < 256; o <<= 1) {
    int a = (t >= o) ? cur[t - o] : 0;
    __syncthreads();
    cur[t] += a;
    __syncthreads();
  }
  int excl = cur[t] - v;
  int node = (b << 8) + t;
  if (node < N) {
    ro[node] = (int)p0 + excl;
    re[node] = (int)p0 + excl + v;
    dinv[node] = rsqrtf((float)(v + 1));  // +1 self-loop
  }
  __syncthreads();
  cur[t] = excl;
  __syncthreads();

  for (int k = t; k < cnt; k += 256) {
    uint pr = lp[k];
    int p = atomicAdd(&cur[(int)(pr & 255u)], 1);
    lout[p] = (int)(pr >> 8);
  }
  __syncthreads();
  for (int k = t; k < cnt; k += 256) csr[p0 + k] = lout[k];
}

// ------------- weight repack into MFMA fragment order (bf16), fused ----------

__device__ inline void pack_one(int idx, const float* __restrict__ W,
                                ushort* __restrict__ Wp, int K, int Ncols) {
  int ksn = K >> 5;
  int l  = idx & 63;
  int ks = (idx >> 6) % ksn;
  int ct = idx / (64 * ksn);
  int col = ct * 16 + (l & 15);
  int kb  = ks * 32 + (l >> 4) * 8;
  short8_t v;
#pragma unroll
  for (int r = 0; r < 8; ++r)
    v[r] = (short)f2bf(W[(size_t)(kb + r) * Ncols + col]);
  *(short8_t*)&Wp[(size_t)idx * 8] = v;
}

__global__ __launch_bounds__(256) void k_packall(const float* __restrict__ Wg,
                                                 const float* __restrict__ W1,
                                                 const float* __restrict__ W2,
                                                 ushort* __restrict__ Wgp,
                                                 ushort* __restrict__ W1p,
                                                 ushort* __restrict__ W2p) {
  int idx = blockIdx.x * 256 + threadIdx.x;
  if (idx < 2048)        pack_one(idx, Wg, Wgp, DN, DN);            // 4*8*64
  else if (idx < 10240)  pack_one(idx - 2048, W1, W1p, DN, H1N);    // 4*32*64
  else if (idx < 26624)  pack_one(idx - 10240, W2, W2p, H1N, H2N);  // 16*16*64
}

// ------ GEMM1: hs = (x @ W_gcn) * dinv[row]; also emits xb = bf16(x) ---------

__global__ __launch_bounds__(256, 4) void k_gemm1(const float* __restrict__ x,
                                                  const ushort* __restrict__ Wgp,
                                                  const float* __restrict__ dinv,
                                                  ushort* __restrict__ hs,
                                                  ushort* __restrict__ xb, int N) {
  __shared__ ushort xT[64 * 128];  // bf16, XOR-swizzled, 16 KB
  int t = threadIdx.x;
  int row0 = blockIdx.x * 64;

#pragma unroll
  for (int i = 0; i < 4; ++i) {
    int c = t + 256 * i;
    int r = c >> 4, d0 = (c & 15) * 8;
    int gr = row0 + r;
    float4 v0 = {0,0,0,0}, v1 = {0,0,0,0};
    if (gr < N) {
      v0 = *(const float4*)(x + (size_t)gr * DN + d0);
      v1 = *(const float4*)(x + (size_t)gr * DN + d0 + 4);
    }
    short8_t p;
    p[0]=(short)f2bf(v0.x); p[1]=(short)f2bf(v0.y); p[2]=(short)f2bf(v0.z); p[3]=(short)f2bf(v0.w);
    p[4]=(short)f2bf(v1.x); p[5]=(short)f2bf(v1.y); p[6]=(short)f2bf(v1.z); p[7]=(short)f2bf(v1.w);
    if (gr < N) *(short8_t*)(xb + (size_t)gr * DN + d0) = p;   // bf16 copy of x
    *(short8_t*)((char*)xT + r * 256 + ((d0 * 2) ^ ((r & 7) << 4))) = p;
  }
  __syncthreads();

  int w = t >> 6, l = t & 63;
  int lr = l & 15, lk = l >> 4;
  const short8_t* pbg = (const short8_t*)Wgp;

  f32x4 acc[4][2];
#pragma unroll
  for (int mf = 0; mf < 4; ++mf)
#pragma unroll
    for (int n = 0; n < 2; ++n) acc[mf][n] = (f32x4){0.f,0.f,0.f,0.f};

  auto g_load = [&](short8_t (&bb)[2], int ks) {
#pragma unroll
    for (int n = 0; n < 2; ++n)
      bb[n] = pbg[((w * 2 + n) * 4 + ks) * 64 + l];
  };
  auto g_mfma = [&](short8_t (&bb)[2], int ks) {
    short8_t a[4];
#pragma unroll
    for (int mf = 0; mf < 4; ++mf) {
      int r = mf * 16 + lr;
      a[mf] = *(const short8_t*)((const char*)xT + r * 256 + ((ks * 64 + lk * 16) ^ ((r & 7) << 4)));
    }
#pragma unroll
    for (int mf = 0; mf < 4; ++mf)
#pragma unroll
      for (int n = 0; n < 2; ++n)
        acc[mf][n] = __builtin_amdgcn_mfma_f32_16x16x32_bf16(a[mf], bb[n], acc[mf][n], 0, 0, 0);
  };

  short8_t bA[2], bB[2];
  g_load(bA, 0);
  g_load(bB, 1); g_mfma(bA, 0);
  g_load(bA, 2); g_mfma(bB, 1);
  g_load(bB, 3); g_mfma(bA, 2);
  g_mfma(bB, 3);

  float dv[4][4];
#pragma unroll
  for (int mf = 0; mf < 4; ++mf)
#pragma unroll
    for (int r2 = 0; r2 < 4; ++r2) {
      int gr = row0 + mf * 16 + lk * 4 + r2;
      dv[mf][r2] = (gr < N) ? dinv[gr] : 0.f;
    }
#pragma unroll
  for (int n = 0; n < 2; ++n) {
    int col = (w * 2 + n) * 16 + lr;
#pragma unroll
    for (int mf = 0; mf < 4; ++mf)
#pragma unroll
      for (int r2 = 0; r2 < 4; ++r2) {
        int gr = row0 + mf * 16 + lk * 4 + r2;
        if (gr < N) hs[(size_t)gr * DN + col] = f2bf(acc[mf][n][r2] * dv[mf][r2]);
      }
  }
}

// --------- aggregation: agg = bf16(relu(dinv*(sum+self) + b) + xb) -----------
// 16 nodes/block, 16 lanes/node, 8 dims (uint4) per lane. 4-deep gather unroll.
// Residual read as bf16 (halves the x-stream in this L3-congested kernel).

__global__ __launch_bounds__(256) void k_agg(const ushort* __restrict__ hs,
                                             const ushort* __restrict__ xb,
                                             const int* __restrict__ csr,
                                             const int* __restrict__ ro,
                                             const int* __restrict__ re,
                                             const float* __restrict__ dinv,
                                             const float* __restrict__ bg,
                                             ushort* __restrict__ aggb, int N) {
  int t = threadIdx.x;
  int node = blockIdx.x * 16 + (t >> 4);
  if (node >= N) return;
  int d0 = (t & 15) * 8;

  int beg = ro[node], end = re[node];
  float dn = dinv[node];
  uint4 selfv = *(const uint4*)(hs + (size_t)node * DN + d0);
  uint4 xv4   = *(const uint4*)(xb + (size_t)node * DN + d0);
  float4 b0 = *(const float4*)(bg + d0);
  float4 b1v = *(const float4*)(bg + d0 + 4);

  float s[8];
#pragma unroll
  for (int i = 0; i < 8; ++i) s[i] = 0.f;

  auto accum = [&](uint4 v) {
    s[0] += asf(v.x << 16); s[1] += asf(v.x & 0xffff0000u);
    s[2] += asf(v.y << 16); s[3] += asf(v.y & 0xffff0000u);
    s[4] += asf(v.z << 16); s[5] += asf(v.z & 0xffff0000u);
    s[6] += asf(v.w << 16); s[7] += asf(v.w & 0xffff0000u);
  };

  int e = beg;
  for (; e + 4 <= end; e += 4) {
    int i0 = csr[e], i1 = csr[e + 1], i2 = csr[e + 2], i3 = csr[e + 3];
    uint4 v0 = *(const uint4*)(hs + (size_t)i0 * DN + d0);
    uint4 v1 = *(const uint4*)(hs + (size_t)i1 * DN + d0);
    uint4 v2 = *(const uint4*)(hs + (size_t)i2 * DN + d0);
    uint4 v3 = *(const uint4*)(hs + (size_t)i3 * DN + d0);
    accum(v0); accum(v1); accum(v2); accum(v3);
  }
  if (e + 2 <= end) {
    int i0 = csr[e], i1 = csr[e + 1];
    uint4 v0 = *(const uint4*)(hs + (size_t)i0 * DN + d0);
    uint4 v1 = *(const uint4*)(hs + (size_t)i1 * DN + d0);
    accum(v0); accum(v1);
    e += 2;
  }
  if (e < end) {
    int i0 = csr[e];
    accum(*(const uint4*)(hs + (size_t)i0 * DN + d0));
  }
  accum(selfv);  // self-loop (pre-scaled by dinv[node])

  float xv[8];
  xv[0] = asf(xv4.x << 16); xv[1] = asf(xv4.x & 0xffff0000u);
  xv[2] = asf(xv4.y << 16); xv[3] = asf(xv4.y & 0xffff0000u);
  xv[4] = asf(xv4.z << 16); xv[5] = asf(xv4.z & 0xffff0000u);
  xv[6] = asf(xv4.w << 16); xv[7] = asf(xv4.w & 0xffff0000u);
  float bv[8] = {b0.x, b0.y, b0.z, b0.w, b1v.x, b1v.y, b1v.z, b1v.w};
  uint outp[4];
#pragma unroll
  for (int i = 0; i < 4; ++i) {
    ushort lo = f2bf(fmaxf(s[2*i]   * dn + bv[2*i],   0.f) + xv[2*i]);
    ushort hi = f2bf(fmaxf(s[2*i+1] * dn + bv[2*i+1], 0.f) + xv[2*i+1]);
    outp[i] = (uint)lo | ((uint)hi << 16);
  }
  *(uint4*)(aggb + (size_t)node * DN + d0) = *(uint4*)outp;
}

// ------------- fused MFMA MLP (SWAPPED operands): D' = W^T-frag x act-frag ---
// 64 rows/block, 512 thr / 8 waves, col-split 8-way, 80 KB LDS -> 2 blocks/CU.

__global__ __launch_bounds__(512, 2) void k_mlp(const ushort* __restrict__ aggb,
                                                const ushort* __restrict__ W1p,
                                                const float* __restrict__ b1,
                                                const ushort* __restrict__ W2p,
                                                const float* __restrict__ b2,
                                                const float* __restrict__ W3,
                                                const float* __restrict__ b3,
                                                float* __restrict__ out, int N) {
  __shared__ ushort aT[64 * 128];   // 16 KB (reused as pf[8][64] floats later)
  __shared__ ushort t1[64 * 512];   // 64 KB
  int t = threadIdx.x;
  int row0 = blockIdx.x * 64;

#pragma unroll
  for (int i = 0; i < 2; ++i) {
    int c = t + 512 * i;
    int r = c >> 4;
    int cb = (c & 15) * 16;
    int gr = row0 + r;
    uint4 v = {0, 0, 0, 0};
    if (gr < N) v = *(const uint4*)(aggb + (size_t)gr * DN + (c & 15) * 8);
    *(uint4*)((char*)aT + r * 256 + (cb ^ ((r & 7) << 4))) = v;
  }
  __syncthreads();

  int w = t >> 6, l = t & 63;
  int lr = l & 15, lk = l >> 4;

  // ---- stage 1 (swapped): acc1[n][mf] = W1'[cols w*64..] x a  ----
  const short8_t* pb1 = (const short8_t*)W1p;
  f32x4 acc1[4][4];   // [n: w1col-tile][mf: node-tile]
#pragma unroll
  for (int n = 0; n < 4; ++n)
#pragma unroll
    for (int mf = 0; mf < 4; ++mf) acc1[n][mf] = (f32x4){0.f,0.f,0.f,0.f};

  auto s1_load = [&](short8_t (&bb)[4], int ks) {
#pragma unroll
    for (int n = 0; n < 4; ++n)
      bb[n] = pb1[((w * 4 + n) * 4 + ks) * 64 + l];
  };
  auto s1_mfma = [&](short8_t (&bb)[4], int ks) {
    short8_t aF[4];
#pragma unroll
    for (int mf = 0; mf < 4; ++mf) {
      int r = mf * 16 + lr;
      aF[mf] = *(const short8_t*)((const char*)aT + r * 256 + ((ks * 64 + lk * 16) ^ ((r & 7) << 4)));
    }
#pragma unroll
    for (int n = 0; n < 4; ++n)
#pragma unroll
      for (int mf = 0; mf < 4; ++mf)
        acc1[n][mf] = __builtin_amdgcn_mfma_f32_16x16x32_bf16(bb[n], aF[mf], acc1[n][mf], 0, 0, 0);
  };

  {
    short8_t bA[4], bB[4];
    s1_load(bA, 0);
    s1_load(bB, 1); s1_mfma(bA, 0);
    s1_load(bA, 2); s1_mfma(bB, 1);
    s1_load(bB, 3); s1_mfma(bA, 2);
    s1_mfma(bB, 3);
  }

  // epilogue: lane holds node = mf*16+lr, w1cols (w*4+n)*16 + lk*4 + r2
#pragma unroll
  for (int n = 0; n < 4; ++n) {
    f32x4 b1v = *(const f32x4*)&b1[(w * 4 + n) * 16 + lk * 4];
#pragma unroll
    for (int mf = 0; mf < 4; ++mf) {
      int rr = mf * 16 + lr;
      ushort4 pk;
      pk.x = f2bf(fmaxf(acc1[n][mf][0] + b1v[0], 0.f));
      pk.y = f2bf(fmaxf(acc1[n][mf][1] + b1v[1], 0.f));
      pk.z = f2bf(fmaxf(acc1[n][mf][2] + b1v[2], 0.f));
      pk.w = f2bf(fmaxf(acc1[n][mf][3] + b1v[3], 0.f));
      int cb2 = ((w * 4 + n) * 32 + lk * 8) ^ ((rr & 7) << 4);
      *(ushort4*)((char*)t1 + rr * 1024 + cb2) = pk;
    }
  }
  __syncthreads();

  // ---- stage 2 (swapped): acc2[n][mf] = W2'[cols w*32..] x t1, K=512 ----
  const short8_t* pb2 = (const short8_t*)W2p;
  f32x4 acc2[2][4];   // [n: w2col-tile][mf: node-tile]
#pragma unroll
  for (int n = 0; n < 2; ++n)
#pragma unroll
    for (int mf = 0; mf < 4; ++mf) acc2[n][mf] = (f32x4){0.f,0.f,0.f,0.f};

  auto s2_load = [&](short8_t (&bb)[2], int ks) {
#pragma unroll
    for (int n = 0; n < 2; ++n)
      bb[n] = pb2[((w * 2 + n) * 16 + ks) * 64 + l];
  };
  auto s2_mfma = [&](short8_t (&bb)[2], int ks) {
    short8_t tF[4];
#pragma unroll
    for (int mf = 0; mf < 4; ++mf) {
      int r = mf * 16 + lr;
      tF[mf] = *(const short8_t*)((const char*)t1 + r * 1024 + ((ks * 64 + lk * 16) ^ ((r & 7) << 4)));
    }
#pragma unroll
    for (int n = 0; n < 2; ++n)
#pragma unroll
      for (int mf = 0; mf < 4; ++mf)
        acc2[n][mf] = __builtin_amdgcn_mfma_f32_16x16x32_bf16(bb[n], tF[mf], acc2[n][mf], 0, 0, 0);
  };

  {
    short8_t c0[2], c1[2], c2[2];
    s2_load(c0, 0); s2_load(c1, 1); s2_load(c2, 2);
    s2_mfma(c0, 0);  s2_load(c0, 3);
    s2_mfma(c1, 1);  s2_load(c1, 4);
    s2_mfma(c2, 2);  s2_load(c2, 5);
    s2_mfma(c0, 3);  s2_load(c0, 6);
    s2_mfma(c1, 4);  s2_load(c1, 7);
    s2_mfma(c2, 5);  s2_load(c2, 8);
    s2_mfma(c0, 6);  s2_load(c0, 9);
    s2_mfma(c1, 7);  s2_load(c1, 10);
    s2_mfma(c2, 8);  s2_load(c2, 11);
    s2_mfma(c0, 9);  s2_load(c0, 12);
    s2_mfma(c1, 10); s2_load(c1, 13);
    s2_mfma(c2, 11); s2_load(c2, 14);
    s2_mfma(c0, 12); s2_load(c0, 15);
    s2_mfma(c1, 13);
    s2_mfma(c2, 14);
    s2_mfma(c0, 15);
  }

  // ---- stage 3 folded: lane holds node = mf*16+lr, w2cols (w*2+n)*16+lk*4+r2
  float po[4];
#pragma unroll
  for (int mf = 0; mf < 4; ++mf) po[mf] = 0.f;
#pragma unroll
  for (int n = 0; n < 2; ++n) {
    int colb = (w * 2 + n) * 16 + lk * 4;
    f32x4 b2v = *(const f32x4*)&b2[colb];
    f32x4 w3v = *(const f32x4*)&W3[colb];
#pragma unroll
    for (int mf = 0; mf < 4; ++mf)
#pragma unroll
      for (int r2 = 0; r2 < 4; ++r2)
        po[mf] += fmaxf(acc2[n][mf][r2] + b2v[r2], 0.f) * w3v[r2];
  }
#pragma unroll
  for (int mf = 0; mf < 4; ++mf) {
    float v = po[mf];
    v += __shfl_xor(v, 16, 64);
    v += __shfl_xor(v, 32, 64);
    po[mf] = v;
  }
  float* pf = (float*)aT;   // aT reads all finished before stage-1->2 barrier
  if (lk == 0) {
#pragma unroll
    for (int mf = 0; mf < 4; ++mf)
      pf[w * 64 + mf * 16 + lr] = po[mf];
  }
  __syncthreads();
  if (t < 64) {
    int gr = row0 + t;
    if (gr < N) {
      float s = b3[0];
#pragma unroll
      for (int ww = 0; ww < 8; ++ww) s += pf[ww * 64 + t];
      out[gr] = s;
    }
  }
}

// ------------------------------- launcher ------------------------------------

extern "C" void kernel_launch(void* const* d_in, const int* in_sizes, int n_in,
                              void* d_out, int out_size, void* d_ws, size_t ws_size,
                              hipStream_t stream) {
  const float* x  = (const float*)d_in[0];
  const int*   ei = (const int*)d_in[1];
  const float* Wg = (const float*)d_in[2];
  const float* bg = (const float*)d_in[3];
  const float* W1 = (const float*)d_in[4];
  const float* b1 = (const float*)d_in[5];
  const float* W2 = (const float*)d_in[6];
  const float* b2 = (const float*)d_in[7];
  const float* W3 = (const float*)d_in[8];
  const float* b3 = (const float*)d_in[9];
  float* out = (float*)d_out;

  const int N = in_sizes[0] / DN;
  const int E = in_sizes[1] / 2;
  const int NB = (N + 255) >> 8;

  char* ws = (char*)d_ws;
  size_t off = 0;
  auto alloc = [&](size_t bytes) -> void* {
    void* p = ws + off;
    off = (off + bytes + 255) & ~(size_t)255;
    return p;
  };
  int*    bcur   = (int*)alloc((size_t)NB * 4);
  int*    ro     = (int*)alloc((size_t)N * 4);
  int*    re     = (int*)alloc((size_t)N * 4);
  float*  dinv   = (float*)alloc((size_t)N * 4);
  int*    csr    = (int*)alloc((size_t)NB * BKT_CAP * 4);
  uint*   pairs  = (uint*)alloc((size_t)NB * BKT_CAP * 4);
  ushort* hsb    = (ushort*)alloc((size_t)N * DN * 2);
  ushort* aggb   = (ushort*)alloc((size_t)N * DN * 2);
  ushort* xbb    = (ushort*)alloc((size_t)N * DN * 2);
  ushort* Wgp    = (ushort*)alloc((size_t)DN * DN * 2);
  ushort* W1p    = (ushort*)alloc((size_t)DN * H1N * 2);
  ushort* W2p    = (ushort*)alloc((size_t)H1N * H2N * 2);
  (void)ws_size; (void)n_in; (void)out_size;

  hipMemsetAsync(bcur, 0, (size_t)NB * 4, stream);

  int nTiles = (E + TILE_A - 1) / TILE_A;
  k_bucketA<<<nTiles, 256, 0, stream>>>(ei, bcur, pairs, E, NB);
  k_bucketB<<<NB, 256, 0, stream>>>(pairs, bcur, csr, ro, re, dinv, N);

  k_packall<<<104, 256, 0, stream>>>(Wg, W1, W2, Wgp, W1p, W2p);

  int nb64 = (N + 63) / 64;
  k_gemm1<<<nb64, 256, 0, stream>>>(x, Wgp, dinv, hsb, xbb, N);
  k_agg<<<(N + 15) / 16, 256, 0, stream>>>(hsb, xbb, csr, ro, re, dinv, bg, aggb, N);
  k_mlp<<<nb64, 512, 0, stream>>>(aggb, W1p, b1, W2p, b2, W3, b3, out, N);
}